// Round 8
// baseline (225.475 us; speedup 1.0000x reference)
//
#include <hip/hip_runtime.h>

// Cumulative product along last dim of (4096, 32768) fp32.
// ONE WAVE PER ROW; 128 chunks of 256 elems (64 lanes x float4, 1KB
// coalesced per vmem op); nt loads/stores; pure-VALU DPP wave scan
// (row_shr 1/2/4/8 + row_bcast15/31 + wave_shr1 + readlane).
// vs R7 (215.7us): PF 4 -> 8 — doubles bytes-in-flight per wave (8KB)
// and the vmcnt slack between refill issue and consume wait. VGPR +16
// is free (occupancy is grid-limited at 4 waves/SIMD).

#define COLS   32768
#define TPB    256
#define WPB    (TPB / 64)        // 4 waves (rows) per block
#define CHUNK  256               // elems per chunk: 64 lanes * 4
#define NCHUNK (COLS / CHUNK)    // 128
#define PF     8                 // prefetch depth in chunks

typedef float f32x4 __attribute__((ext_vector_type(4)));

#define ONE_BITS 0x3f800000      // 1.0f as int (multiplicative identity)

// x * dpp_moved(x); masked-off/invalid lanes contribute 1.0f.
template <int CTRL, int RM, int BM>
__device__ __forceinline__ float mul_dpp(float x) {
    int s = __builtin_amdgcn_update_dpp(ONE_BITS, __float_as_int(x),
                                        CTRL, RM, BM, false);
    return x * __int_as_float(s);
}

__global__ __launch_bounds__(TPB) void cumprod_rows(const float* __restrict__ x,
                                                    float* __restrict__ out) {
    const int lane = threadIdx.x & 63;
    const int wid  = threadIdx.x >> 6;
    const int row  = blockIdx.x * WPB + wid;

    const size_t base = (size_t)row * (size_t)COLS + (size_t)lane * 4;
    const float* px = x + base;
    float*       po = out + base;

    // ---- prime the prefetch ring (static indices only) ----
    f32x4 buf[PF];
    #pragma unroll
    for (int j = 0; j < PF; ++j)
        buf[j] = __builtin_nontemporal_load(
            reinterpret_cast<const f32x4*>(px + j * CHUNK));

    float carry = 1.0f;

    for (int cc = 0; cc < NCHUNK; cc += PF) {
        #pragma unroll
        for (int j = 0; j < PF; ++j) {
            f32x4 v = buf[j];

            // refill this ring slot from PF chunks ahead (uniform branch)
            const int nc = cc + PF + j;
            if (nc < NCHUNK)
                buf[j] = __builtin_nontemporal_load(
                    reinterpret_cast<const f32x4*>(px + nc * CHUNK));

            // in-lane inclusive scan of 4 elements
            v[1] *= v[0];
            v[2] *= v[1];
            v[3] *= v[2];

            // ---- wave-wide inclusive scan, pure VALU DPP ----
            float t = v[3];
            t = mul_dpp<0x111, 0xf, 0xf>(t);   // row_shr:1
            t = mul_dpp<0x112, 0xf, 0xf>(t);   // row_shr:2
            t = mul_dpp<0x114, 0xf, 0xf>(t);   // row_shr:4
            t = mul_dpp<0x118, 0xf, 0xf>(t);   // row_shr:8  (rows of 16 done)
            t = mul_dpp<0x142, 0xa, 0xf>(t);   // row_bcast:15 -> rows 1,3
            t = mul_dpp<0x143, 0xc, 0xf>(t);   // row_bcast:31 -> rows 2,3

            // exclusive prefix: lane i <- t[i-1], lane 0 <- 1.0 (wave_shr:1)
            float ex = __int_as_float(__builtin_amdgcn_update_dpp(
                ONE_BITS, __float_as_int(t), 0x138, 0xf, 0xf, false));

            const float m = carry * ex;

            // wave total (lane 63) -> next carry; uniform SGPR multiply
            carry *= __int_as_float(
                __builtin_amdgcn_readlane(__float_as_int(t), 63));

            f32x4 o;
            o[0] = v[0] * m;
            o[1] = v[1] * m;
            o[2] = v[2] * m;
            o[3] = v[3] * m;
            __builtin_nontemporal_store(
                o, reinterpret_cast<f32x4*>(po + (cc + j) * CHUNK));
        }
    }
}

extern "C" void kernel_launch(void* const* d_in, const int* in_sizes, int n_in,
                              void* d_out, int out_size, void* d_ws, size_t ws_size,
                              hipStream_t stream) {
    const float* x = (const float*)d_in[0];
    float* out = (float*)d_out;
    const int rows = out_size / COLS;          // 4096
    cumprod_rows<<<rows / WPB, TPB, 0, stream>>>(x, out);
}